// Round 12
// baseline (149.986 us; speedup 1.0000x reference)
//
#include <hip/hip_runtime.h>

typedef _Float16 half_t;
typedef half_t half2_t __attribute__((ext_vector_type(2)));
typedef half_t half8  __attribute__((ext_vector_type(8)));
typedef unsigned int uint_t;
typedef uint_t uint4v __attribute__((ext_vector_type(4)));
typedef float float4v __attribute__((ext_vector_type(4)));

#define B_  64
#define T_  256
#define F_  16
#define H_  128
#define HP  160   // padded batch stride (320 B) -> bufB reads on banks 16-31 (R11-verified)
#define LOG2E 1.44269504f

__device__ __forceinline__ float rcp_(float x)  { return __builtin_amdgcn_rcpf(x); }
__device__ __forceinline__ float sigm2(float x) { return rcp_(1.0f + __builtin_amdgcn_exp2f(x * -LOG2E)); }
__device__ __forceinline__ float tanh2(float x) { return fmaf(rcp_(1.0f + __builtin_amdgcn_exp2f(x * (-2.0f * LOG2E))), 2.0f, -1.0f); }
__device__ __forceinline__ float sigm(float x)  { return rcp_(1.0f + __expf(-x)); }

// Kernel 0: rank batches by window midpoint; pair consecutive ranks (similar windows
// -> union ~ max not sum). pairs[p] = {bA<<8|bB, sA<<16|eA, sB<<16|eB, su<<16|eu}.
__global__ void make_sched(const int* __restrict__ index, int* __restrict__ pairs) {
    __shared__ int ss[B_], ee[B_], mid[B_], bo[B_];
    const int t = threadIdx.x;                 // 64
    const int s = index[2 * t], e = index[2 * t + 1];
    ss[t] = s; ee[t] = e; mid[t] = s + e;
    __syncthreads();
    int m = mid[t], r = 0;
    for (int j = 0; j < B_; ++j) r += (mid[j] < m) || (mid[j] == m && j < t);
    bo[r] = t;
    __syncthreads();
    if (t < 32) {
        int bA = bo[2 * t], bB = bo[2 * t + 1];
        int su = min(ss[bA], ss[bB]), eu = max(ee[bA], ee[bB]);
        int4 v;
        v.x = (bA << 8) | bB;
        v.y = (ss[bA] << 16) | ee[bA];
        v.z = (ss[bB] << 16) | ee[bB];
        v.w = (su << 16) | eu;
        ((int4*)pairs)[t] = v;
    }
}

// Kernel 1 (verified R7-R11): W_hh [F,4H,H] fp32 -> f16 B-frags for mfma_f32_16x16x32_f16.
// Lane `lane` of tile w8, frag q=m*4+kt, dword e2 holds the f16 pair for
// k = kt*32 + (lane>>4)*8 + 2*e2 (+1), col g = 128*m + 16*w8 + (lane&15).
__global__ void repack_w(const float* __restrict__ whh, uint_t* __restrict__ wt) {
    const int f = blockIdx.x, w = blockIdx.y, tid = threadIdx.x;  // 256 threads
    const int lane = tid & 63, q4 = tid >> 6;
    const int li = lane & 15, lg = lane >> 4;
    const float* base = whh + (size_t)f * 512 * 128;
#pragma unroll
    for (int qq = 0; qq < 4; ++qq) {
        const int qf = q4 * 4 + qq;
        const int m = qf >> 2, kt = qf & 3;
        const int g512 = 128 * m + 16 * w + li;
        uint_t tmp[4];
#pragma unroll
        for (int e2 = 0; e2 < 4; ++e2) {
            int k = kt * 32 + lg * 8 + 2 * e2;
            half2_t h;
            h[0] = (half_t)base[g512 * 128 + k];
            h[1] = (half_t)base[g512 * 128 + k + 1];
            tmp[e2] = __builtin_bit_cast(uint_t, h);
        }
        uint4 out = { tmp[0], tmp[1], tmp[2], tmp[3] };
        ((uint4*)wt)[(((size_t)f * 8 + w) * 16 + qf) * 64 + lane] = out;
    }
}

// Kernel 2: one block per (f, chain-PAIR); 4 waves x 256 thr (R11 had 8 waves: the
// 4x ds_read_b128 A-frag reads are col-tile-independent, so 8 waves paid 2x redundant
// LDS traffic -> LDS pipe was ~74% busy, the top shared resource). Wave w owns
// cell-blocks {w, w+4} x 4 gate types = 32 B-fragsets (128 VGPRs). A rows 0-7 =
// batch A's h, 8-15 = batch B's. Lane (li,lg): batch csel=lg>>1, writes cell
// 16w+li+64*(lg&1) -> all 64 lanes write, each cell exactly once. MFMA C-in = zero
// tuple (z4, no per-step v_mov init); x*wih+bias added after the chain.
__global__ __launch_bounds__(256, 2) void lstm_mfma(
    const float* __restrict__ x, const uint_t* __restrict__ wt,
    const float* __restrict__ wih_g, const float* __restrict__ bias_g,
    const int* __restrict__ pairs, float* __restrict__ hout)
{
    __shared__ float xsh[2][T_ + 8];
    __shared__ alignas(16) half_t hbuf[2][2][HP];   // [buf][batch][cell], padded

    const int f = blockIdx.x & 15;
    const int4 pv = ((const int4*)pairs)[blockIdx.x >> 4];
    const int bA = pv.x >> 8, bB = pv.x & 255;
    const int sA = pv.y >> 16, eA = pv.y & 0xffff;
    const int sB = pv.z >> 16, eB = pv.z & 0xffff;
    const int su = pv.w >> 16, eu = pv.w & 0xffff;

    const int tid = threadIdx.x, lane = tid & 63, w = tid >> 6;   // w = 0..3
    const int li = lane & 15, lg = lane >> 4;
    const int hsel = li >> 3;                 // A-frag row group: 0 -> batch A, 1 -> B
    const int csel = lg >> 1;                 // C row group: 0 -> batch A, 1 -> B
    const int sub  = lg & 1;                  // which of this lane's 2 cells it stores
    const int cell0 = 16 * w + li;            // cell-block w
    const int wcell = cell0 + 64 * sub;       // the cell this lane stores

    // ---- opaque weight preload: 32 x global_load_dwordx4 (proven resident R4-R11) ----
    uint4v wr[2][16];
    {
#pragma unroll
        for (int cb = 0; cb < 2; ++cb) {
            const char* ws = (const char*)wt + ((((size_t)f * 8 + (w + 4 * cb)) * 16) * 64 + lane) * 16;
#pragma unroll
            for (int q = 0; q < 16; ++q) {
                unsigned long long a = (unsigned long long)(ws + (size_t)q * 1024);
                asm volatile("global_load_dwordx4 %0, %1, off" : "=v"(wr[cb][q]) : "v"(a));
            }
        }
        asm volatile("s_waitcnt vmcnt(0)");
        __builtin_amdgcn_sched_barrier(0);
    }

    float wih[2][4], bb4[2][4];
#pragma unroll
    for (int cb = 0; cb < 2; ++cb)
#pragma unroll
        for (int m = 0; m < 4; ++m) {
            wih[cb][m] = wih_g[f * 512 + 128 * m + cell0 + 64 * cb];
            bb4[cb][m] = bias_g[f * 512 + 128 * m + cell0 + 64 * cb];
        }

    const int myb = csel ? bB : bA;
    const int mys = csel ? sB : sA;
    const int mye = csel ? eB : eA;

    // stage x rows for both batches (2 per thread); zero h buffer 0 (both batches)
#pragma unroll
    for (int j = 0; j < 2; ++j) {
        int idx = tid + 256 * j;
        int bb_ = idx >> 8, tt = idx & 255;
        xsh[bb_][tt] = x[((size_t)(bb_ ? bB : bA) * T_ + tt) * F_ + f];
    }
    if (tid < 2 * H_) hbuf[0][tid >> 7][tid & 127] = (half_t)0.0f;

    float cst[2] = {0.f, 0.f}, hst[2] = {0.f, 0.f};
    const float4v z4 = {0.f, 0.f, 0.f, 0.f};
    int pp = 0;
    __syncthreads();

    for (int t = su; t < eu; ++t) {
        // A-frags: broadcast reads of current h for this lane's A-row batch
        const half_t* hb = &hbuf[pp][hsel][lg * 8];
        half8 a0 = *(const half8*)(hb + 0);
        half8 a1 = *(const half8*)(hb + 32);
        half8 a2 = *(const half8*)(hb + 64);
        half8 a3 = *(const half8*)(hb + 96);
        float xt = xsh[csel][t];

        float gv[2][4];
#pragma unroll
        for (int cb = 0; cb < 2; ++cb)
#pragma unroll
            for (int m = 0; m < 4; ++m) {
                float4v ci;
                ci = __builtin_amdgcn_mfma_f32_16x16x32_f16(a0, __builtin_bit_cast(half8, wr[cb][m * 4 + 0]), z4, 0, 0, 0);
                ci = __builtin_amdgcn_mfma_f32_16x16x32_f16(a1, __builtin_bit_cast(half8, wr[cb][m * 4 + 1]), ci, 0, 0, 0);
                ci = __builtin_amdgcn_mfma_f32_16x16x32_f16(a2, __builtin_bit_cast(half8, wr[cb][m * 4 + 2]), ci, 0, 0, 0);
                ci = __builtin_amdgcn_mfma_f32_16x16x32_f16(a3, __builtin_bit_cast(half8, wr[cb][m * 4 + 3]), ci, 0, 0, 0);
                gv[cb][m] = ci[0] + fmaf(xt, wih[cb][m], bb4[cb][m]);
            }

        bool mk = (t >= mys) & (t < mye);
#pragma unroll
        for (int cb = 0; cb < 2; ++cb) {
            float gi = sigm2(gv[cb][0]);
            float gf = sigm2(gv[cb][1]);
            float gg = tanh2(gv[cb][2]);
            float go = sigm2(gv[cb][3]);
            float cn = fmaf(gf, cst[cb], gi * gg);
            cst[cb] = mk ? cn : cst[cb];
            float hn = go * tanh2(cst[cb]);
            hst[cb] = mk ? hn : hst[cb];
        }

        hbuf[pp ^ 1][csel][wcell] = (half_t)hst[sub];   // every lane stores one cell
        __syncthreads();
        pp ^= 1;
    }

    hout[((size_t)myb * F_ + f) * H_ + wcell] = hst[sub];
}

// Kernel 3: per-batch epilogue: mean over H -> conv3 (pad 1) -> sigmoid gate -> gated fc.
__global__ void epilogue(const float* __restrict__ hout, const float* __restrict__ conv_w,
                         const float* __restrict__ fc_w, const float* __restrict__ fc_b,
                         float* __restrict__ out)
{
    const int b = blockIdx.x, t = threadIdx.x;   // 128 threads
    const int lane = t & 63, wv = t >> 6;
    __shared__ float part[2][16];
    __shared__ float gate_sh[16];

    float hv[16];
#pragma unroll
    for (int f = 0; f < 16; ++f) hv[f] = hout[((size_t)b * 16 + f) * 128 + t];

#pragma unroll
    for (int f = 0; f < 16; ++f) {
        float s = hv[f];
#pragma unroll
        for (int off = 32; off >= 1; off >>= 1) s += __shfl_down(s, off, 64);
        if (lane == 0) part[wv][f] = s;
    }
    __syncthreads();
    if (t < 16) gate_sh[t] = (part[0][t] + part[1][t]) * (1.0f / 128.0f);
    __syncthreads();
    float gate = 0.0f;
    if (t < 16) {
        float l  = (t > 0)  ? gate_sh[t - 1] : 0.0f;
        float mi = gate_sh[t];
        float r  = (t < 15) ? gate_sh[t + 1] : 0.0f;
        gate = sigm(fmaf(l, conv_w[0], fmaf(mi, conv_w[1], r * conv_w[2])));
    }
    __syncthreads();
    if (t < 16) gate_sh[t] = gate;
    __syncthreads();

    float acc0 = 0.0f, acc1 = 0.0f;
    const float2* fw2 = (const float2*)fc_w;
#pragma unroll
    for (int f = 0; f < 16; ++f) {
        float hg = hv[f] * gate_sh[f];
        float2 w2 = fw2[f * 128 + t];
        acc0 = fmaf(hg, w2.x, acc0);
        acc1 = fmaf(hg, w2.y, acc1);
    }
#pragma unroll
    for (int off = 32; off >= 1; off >>= 1) {
        acc0 += __shfl_down(acc0, off, 64);
        acc1 += __shfl_down(acc1, off, 64);
    }
    if (lane == 0) { part[wv][0] = acc0; part[wv][1] = acc1; }
    __syncthreads();
    if (t == 0) {
        out[b * 2 + 0] = part[0][0] + part[1][0] + fc_b[0];
        out[b * 2 + 1] = part[0][1] + part[1][1] + fc_b[1];
    }
}

extern "C" void kernel_launch(void* const* d_in, const int* in_sizes, int n_in,
                              void* d_out, int out_size, void* d_ws, size_t ws_size,
                              hipStream_t stream) {
    const float* x      = (const float*)d_in[0];
    const int*   index  = (const int*)  d_in[1];
    const float* W_ih   = (const float*)d_in[2];
    const float* W_hh   = (const float*)d_in[3];
    const float* bias   = (const float*)d_in[4];
    const float* conv_w = (const float*)d_in[5];
    const float* fc_w   = (const float*)d_in[6];
    const float* fc_b   = (const float*)d_in[7];
    float* out = (float*)d_out;

    uint_t* wt    = (uint_t*)d_ws;                                     // 2 MB
    float*  hout  = (float*)((char*)d_ws + 2 * 1024 * 1024);           // 512 KB
    int*    pairs = (int*)((char*)d_ws + 2 * 1024 * 1024 + 512 * 1024); // 512 B

    make_sched<<<1, 64, 0, stream>>>(index, pairs);
    repack_w<<<dim3(F_, 8), 256, 0, stream>>>(W_hh, wt);
    lstm_mfma<<<512, 256, 0, stream>>>(x, wt, W_ih, bias, pairs, hout);
    epilogue<<<B_, 128, 0, stream>>>(hout, conv_w, fc_w, fc_b, out);
}